// Round 9
// baseline (206.981 us; speedup 1.0000x reference)
//
#include <hip/hip_runtime.h>
#include <hip/hip_fp16.h>

#define N_NODES 50000
#define N_EDGES 800000
#define IN_FEATS 128
#define HD 128            // HEADS*OUT_FEATS
#define LOG2E 1.4426950408889634f

#define NB1 200           // pass-1 radix blocks
#define EPB1 4000         // edges per pass-1 block (200*4000 == E exactly)
#define NBUK 196          // buckets = ceil(N_NODES/256)
#define MTAB (NBUK * NB1) // 39200 histogram table entries (u16)
#define MB_SCAN 154       // ceil(MTAB/256)
#define EBUF 6144         // LDS edge staging per bucket (mean 4081, max ~4400)
#define PREPN 192         // prep blocks (192*256 == 24*4*64*8)
#define PGRID 782         // proj blocks = ceil((N_NODES/16)/4)

typedef __attribute__((ext_vector_type(8))) short bf16x8;
typedef __attribute__((ext_vector_type(4))) float floatx4;
typedef _Float16 h2 __attribute__((ext_vector_type(2)));

#if __has_builtin(__builtin_amdgcn_exp2f)
#define EXP2F(x) __builtin_amdgcn_exp2f(x)
#else
#define EXP2F(x) __expf((x) * 0.6931471805599453f)
#endif

static __device__ __forceinline__ unsigned short f2bf(float x) {
    unsigned int u = __float_as_uint(x);
    return (unsigned short)((u + 0x7FFFu + ((u >> 16) & 1u)) >> 16);   // RN-even
}
static __device__ __forceinline__ float bf2f(unsigned short h) {
    return __uint_as_float((unsigned int)h << 16);
}
static __device__ __forceinline__ unsigned int pk(float a, float b) {
    return (unsigned int)__half_as_ushort(__float2half(a)) |
           ((unsigned int)__half_as_ushort(__float2half(b)) << 16);
}
static __device__ __forceinline__ h2 u2h2(unsigned int u) {
    return __builtin_bit_cast(h2, u);
}

// ---------------------------------------------------------------------------
// K1: prep (weight swizzle into MFMA A-fragment order, log2e pre-scale) +
//     pass-1 radix histogram of dst>>8 (LDS atomics, u16 table).
// ---------------------------------------------------------------------------
__global__ __launch_bounds__(256) void prep_hist_kernel(
    const float* __restrict__ W0, const float* __restrict__ W1,
    const float* __restrict__ W2, unsigned short* __restrict__ Bsw,
    const int* __restrict__ dst, unsigned short* __restrict__ Htab) {
    __shared__ int h[NBUK];
    if (blockIdx.x < PREPN) {
        int idx = blockIdx.x * 256 + threadIdx.x;    // < 49152 exactly
        int j = idx & 7;
        int l = (idx >> 3) & 63;
        int q = (idx >> 9) & 3;
        int t = idx >> 11;                           // 0..23
        int k = q * 32 + ((l >> 4) << 3) + j;
        int c = ((t & 7) << 4) + (l & 15);
        int m = t >> 3;
        const float* W = (m == 0) ? W0 : ((m == 1) ? W1 : W2);
        float w = W[(size_t)c * IN_FEATS + k];
        if (m < 2) w *= LOG2E;
        Bsw[idx] = f2bf(w);
        return;
    }
    int blk = blockIdx.x - PREPN;                    // 0..NB1-1
    for (int i = threadIdx.x; i < NBUK; i += 256) h[i] = 0;
    __syncthreads();
    int base = blk * EPB1;
    for (int i = threadIdx.x; i < EPB1; i += 256)
        atomicAdd(&h[dst[base + i] >> 8], 1);
    __syncthreads();
    for (int b = threadIdx.x; b < NBUK; b += 256)
        Htab[b * NB1 + blk] = (unsigned short)h[b];  // counts <= 4000 < 65536
}

// ---------------------------------------------------------------------------
// K2: single-kernel exclusive scan of the u16 Htab. Block b redundantly sums
// its prefix columns (<=153 independent coalesced u16 loads per thread), then
// in-tile shfl scan. No inter-kernel dependency.
// ---------------------------------------------------------------------------
__global__ __launch_bounds__(256) void scan_kernel(
    const unsigned short* __restrict__ Htab, int* __restrict__ HtabS) {
    int t = threadIdx.x, b = blockIdx.x;
    int lane = t & 63, w = t >> 6;
    int part = 0;
    for (int T = 0; T < b; ++T) part += (int)Htab[T * 256 + t];
#pragma unroll
    for (int d = 32; d > 0; d >>= 1) part += __shfl_down(part, d);
    __shared__ int ws[4], ws2[4];
    if (lane == 0) ws[w] = part;
    __syncthreads();
    int base = ws[0] + ws[1] + ws[2] + ws[3];
    int i = b * 256 + t;
    int v = (i < MTAB) ? (int)Htab[i] : 0;
    int x = v;
#pragma unroll
    for (int d = 1; d < 64; d <<= 1) { int up = __shfl_up(x, d); if (lane >= d) x += up; }
    if (lane == 63) ws2[w] = x;
    __syncthreads();
    for (int ww = 0; ww < w; ++ww) base += ws2[ww];
    if (i < MTAB) HtabS[i] = base + x - v;
}

// ---------------------------------------------------------------------------
// K3: fused MFMA projection + pass-1 scatter (precomputed HtabS bases).
// ---------------------------------------------------------------------------
__global__ __launch_bounds__(256) void proj_scatter_kernel(
    const float* __restrict__ feat, const unsigned short* __restrict__ Bsw,
    const float* __restrict__ b_src, const float* __restrict__ b_dst,
    const float* __restrict__ b_v,
    unsigned short* __restrict__ gsv, unsigned short* __restrict__ fdh,
    const int* __restrict__ src, const int* __restrict__ dst,
    const int* __restrict__ HtabS, unsigned int* __restrict__ tmp) {
    __shared__ int curl[NBUK];
    if (blockIdx.x >= PGRID) {
        int blk = blockIdx.x - PGRID;
        for (int b = threadIdx.x; b < NBUK; b += 256) curl[b] = HtabS[b * NB1 + blk];
        __syncthreads();
        int ebase = blk * EPB1;
        for (int i = threadIdx.x; i < EPB1; i += 256) {
            int d = dst[ebase + i];
            int s = src[ebase + i];
            int p = atomicAdd(&curl[d >> 8], 1);     // LDS atomic
            tmp[p] = (unsigned int)s | ((unsigned int)(d & 255) << 16);
        }
        return;
    }
    int wave = threadIdx.x >> 6, lane = threadIdx.x & 63;
    int tile = blockIdx.x * 4 + wave;
    if (tile >= N_NODES / 16) return;
    int row0 = tile * 16;
    int r16 = lane & 15, quad = lane >> 4;
    size_t node = (size_t)(row0 + r16);

    bf16x8 Fh[4], Fl[4];
    const float* frow = feat + node * IN_FEATS + quad * 8;
#pragma unroll
    for (int q = 0; q < 4; ++q) {
        float4 x0 = *(const float4*)(frow + q * 32);
        float4 x1 = *(const float4*)(frow + q * 32 + 4);
        float xs[8] = {x0.x, x0.y, x0.z, x0.w, x1.x, x1.y, x1.z, x1.w};
#pragma unroll
        for (int j = 0; j < 8; ++j) {
            unsigned short hh = f2bf(xs[j]);
            Fh[q][j] = (short)hh;
            Fl[q][j] = (short)f2bf(xs[j] - bf2f(hh));
        }
    }

#pragma unroll 1
    for (int tt = 0; tt < 8; ++tt) {
        floatx4 as = {0.f,0.f,0.f,0.f}, ad = {0.f,0.f,0.f,0.f}, av = {0.f,0.f,0.f,0.f};
#pragma unroll
        for (int q = 0; q < 4; ++q) {
            bf16x8 ws = *(const bf16x8*)(Bsw + ((((tt)      * 4 + q) * 64 + lane) << 3));
            bf16x8 wd = *(const bf16x8*)(Bsw + ((((8 + tt)  * 4 + q) * 64 + lane) << 3));
            bf16x8 wv = *(const bf16x8*)(Bsw + ((((16 + tt) * 4 + q) * 64 + lane) << 3));
            as = __builtin_amdgcn_mfma_f32_16x16x32_bf16(ws, Fh[q], as, 0, 0, 0);
            as = __builtin_amdgcn_mfma_f32_16x16x32_bf16(ws, Fl[q], as, 0, 0, 0);
            ad = __builtin_amdgcn_mfma_f32_16x16x32_bf16(wd, Fh[q], ad, 0, 0, 0);
            ad = __builtin_amdgcn_mfma_f32_16x16x32_bf16(wd, Fl[q], ad, 0, 0, 0);
            av = __builtin_amdgcn_mfma_f32_16x16x32_bf16(wv, Fh[q], av, 0, 0, 0);
            av = __builtin_amdgcn_mfma_f32_16x16x32_bf16(wv, Fl[q], av, 0, 0, 0);
        }
        int cbase = (tt << 4) + (quad << 2);
        float4 bs = *(const float4*)(b_src + cbase);
        float4 bd = *(const float4*)(b_dst + cbase);
        float4 bv = *(const float4*)(b_v   + cbase);
        uint4 o;
        o.x = pk(as[0] + bs.x * LOG2E, as[1] + bs.y * LOG2E);
        o.y = pk(av[0] + bv.x,         av[1] + bv.y);
        o.z = pk(as[2] + bs.z * LOG2E, as[3] + bs.w * LOG2E);
        o.w = pk(av[2] + bv.z,         av[3] + bv.w);
        *(uint4*)(gsv + node * 256 + (cbase << 1)) = o;
        uint2 od;
        od.x = pk(ad[0] + bd.x * LOG2E, ad[1] + bd.y * LOG2E);
        od.y = pk(ad[2] + bd.z * LOG2E, ad[3] + bd.w * LOG2E);
        *(uint2*)(fdh + node * 128 + cbase) = od;
    }
}

// ---------------------------------------------------------------------------
// K4: pass-2 bin. One block per bucket; LDS staging; coalesced ssort flush.
// ---------------------------------------------------------------------------
__global__ __launch_bounds__(256) void bin_kernel(
    const unsigned int* __restrict__ tmp, const int* __restrict__ HtabS,
    int* __restrict__ off, int* __restrict__ ssort) {
    __shared__ unsigned int ebuf[EBUF];
    __shared__ unsigned short obuf[EBUF];
    __shared__ int cnt_l[256];
    __shared__ int wsum[4];
    int b = blockIdx.x, t = threadIdx.x, lane = t & 63, w = t >> 6;
    int start = HtabS[b * NB1];
    int end = (b == NBUK - 1) ? N_EDGES : HtabS[(b + 1) * NB1];
    int cnt0 = end - start;
    cnt_l[t] = 0;
    __syncthreads();
    bool staged = (cnt0 <= EBUF);
    for (int i = t; i < cnt0; i += 256) {
        unsigned int e = tmp[start + i];
        if (staged) ebuf[i] = e;
        atomicAdd(&cnt_l[e >> 16], 1);
    }
    __syncthreads();
    int v = cnt_l[t];
    int x = v;
#pragma unroll
    for (int d = 1; d < 64; d <<= 1) { int up = __shfl_up(x, d); if (lane >= d) x += up; }
    if (lane == 63) wsum[w] = x;
    __syncthreads();
    int basex = 0;
    for (int ww = 0; ww < w; ++ww) basex += wsum[ww];
    int excl = basex + x - v;                  // exclusive within bucket
    int node = b * 256 + t;
    if (node < N_NODES) off[node] = start + excl;
    if (b == NBUK - 1) {
        if (t == 0) off[N_NODES] = N_EDGES;
        if (t < 8) ssort[N_EDGES + t] = 0;     // pads for gather prefetch
    }
    __syncthreads();
    cnt_l[t] = excl;                           // becomes cursor
    __syncthreads();
    if (staged) {
        for (int i = t; i < cnt0; i += 256) {
            unsigned int e = ebuf[i];
            int p = atomicAdd(&cnt_l[e >> 16], 1);
            obuf[p] = (unsigned short)(e & 0xFFFFu);
        }
        __syncthreads();
        for (int i = t; i < cnt0; i += 256)    // coalesced flush
            ssort[start + i] = (int)obuf[i];
    } else {
        for (int i = t; i < cnt0; i += 256) {
            unsigned int e = tmp[start + i];
            int p = atomicAdd(&cnt_l[e >> 16], 1);
            ssort[start + p] = (int)(e & 0xFFFFu);
        }
    }
}

// ---------------------------------------------------------------------------
// K5: gather. One wave per dst node, channel pair per lane (uint2/edge-row,
// one full row per wave-load). FOUR interleaved software-pipelined edge
// streams for MLP. Logits in packed fp16 (leaky via 0.6a+0.4|a|, |a| = one
// v_and), exp2 (weights pre-scaled by log2e), fp32 accumulation.
// ---------------------------------------------------------------------------
__global__ __launch_bounds__(128) void gather_kernel(
    const unsigned short* __restrict__ gsv, const unsigned short* __restrict__ fdh,
    const int* __restrict__ off, const int* __restrict__ ssort,
    float* __restrict__ out, int n) {
    int wid = __builtin_amdgcn_readfirstlane((int)((blockIdx.x * 128 + threadIdx.x) >> 6));
    int lane = threadIdx.x & 63;
    if (wid >= n) return;
    unsigned int fdu = *(const unsigned int*)(fdh + (size_t)wid * 128 + lane * 2);
    h2 fd2 = u2h2(fdu);
    const h2 c06 = {(_Float16)0.6f, (_Float16)0.6f};
    const h2 c04 = {(_Float16)0.4f, (_Float16)0.4f};

    float nx[4], ny[4], dx[4], dy[4];
#pragma unroll
    for (int k = 0; k < 4; ++k) { nx[k] = 0.f; ny[k] = 0.f; dx[k] = 0.f; dy[k] = 0.f; }

    int beg = off[wid], end = off[wid + 1];
    int deg = end - beg;
    int iters = (deg + 3) >> 2;

    if (iters > 0) {
        uint2 g[4];
#pragma unroll
        for (int k = 0; k < 4; ++k) {
            int idx = beg + k;
            int s = (idx < end) ? ssort[idx] : 0;
            g[k] = *(const uint2*)(gsv + (size_t)s * 256 + lane * 4);
        }
        for (int j = 0; j < iters; ++j) {
            int b4 = beg + 4 * j + 4;
            uint2 gn[4];
#pragma unroll
            for (int k = 0; k < 4; ++k) {
                int idx = b4 + k;                       // <= end+6 <= E+6 (8 pads)
                int s = (idx < end) ? ssort[idx] : 0;   // row 0 stays cache-hot
                gn[k] = *(const uint2*)(gsv + (size_t)s * 256 + lane * 4);
            }
#pragma unroll
            for (int k = 0; k < 4; ++k) {
                h2 fs = u2h2(g[k].x);
                h2 a = fs + fd2;                                        // v_pk_add_f16
                h2 aa = u2h2(__builtin_bit_cast(unsigned int, a) & 0x7FFF7FFFu);
                h2 al = a * c06 + aa * c04;                             // pk_mul + pk_fma
                float x0 = EXP2F((float)al.x);
                float x1 = EXP2F((float)al.y);
                bool valid = (4 * j + k) < deg;
                if (!valid) { x0 = 0.f; x1 = 0.f; }
                float2 fv = __half22float2(*(const __half2*)&g[k].y);
                dx[k] += x0; dy[k] += x1;
                nx[k] = fmaf(x0, fv.x, nx[k]); ny[k] = fmaf(x1, fv.y, ny[k]);
                g[k] = gn[k];
            }
        }
    }
    float dxs = (dx[0] + dx[1]) + (dx[2] + dx[3]);
    float dys = (dy[0] + dy[1]) + (dy[2] + dy[3]);
    float nxs = (nx[0] + nx[1]) + (nx[2] + nx[3]);
    float nys = (ny[0] + ny[1]) + (ny[2] + ny[3]);
    float2 o;
    o.x = (dxs > 0.f) ? nxs / dxs : 0.f;
    o.y = (dys > 0.f) ? nys / dys : 0.f;
    *(float2*)&out[(size_t)wid * HD + lane * 2] = o;
}

// ---------------------------------------------------------------------------
extern "C" void kernel_launch(void* const* d_in, const int* in_sizes, int n_in,
                              void* d_out, int out_size, void* d_ws, size_t ws_size,
                              hipStream_t stream) {
    const float* feat  = (const float*)d_in[0];
    const float* W_src = (const float*)d_in[1];
    const float* b_src = (const float*)d_in[2];
    const float* W_dst = (const float*)d_in[3];
    const float* b_dst = (const float*)d_in[4];
    const float* W_v   = (const float*)d_in[5];
    const float* b_v   = (const float*)d_in[6];
    const int*   src   = (const int*)d_in[7];
    const int*   dst   = (const int*)d_in[8];
    float* out = (float*)d_out;

    // workspace layout
    unsigned short* gsv  = (unsigned short*)d_ws;                // N*256 u16
    unsigned short* fdh  = gsv + (size_t)N_NODES * 256;          // N*128 u16
    unsigned short* Bsw  = fdh + (size_t)N_NODES * 128;          // 49152 u16
    unsigned short* Htab = Bsw + 24 * 4 * 64 * 8;                // MTAB u16
    int* HtabS = (int*)(Htab + MTAB);                            // MTAB int
    int* off   = HtabS + MTAB;                                   // N+1
    int* ssort = off + (N_NODES + 1);                            // E+8
    unsigned int* tmp = (unsigned int*)(ssort + N_EDGES + 8);    // E

    prep_hist_kernel<<<PREPN + NB1, 256, 0, stream>>>(W_src, W_dst, W_v, Bsw, dst, Htab);

    scan_kernel<<<MB_SCAN, 256, 0, stream>>>(Htab, HtabS);

    proj_scatter_kernel<<<PGRID + NB1, 256, 0, stream>>>(
        feat, Bsw, b_src, b_dst, b_v, gsv, fdh, src, dst, HtabS, tmp);

    bin_kernel<<<NBUK, 256, 0, stream>>>(tmp, HtabS, off, ssort);

    gather_kernel<<<(N_NODES * 64) / 128, 128, 0, stream>>>(gsv, fdh, off, ssort, out, N_NODES);
}

// Round 10
// 187.605 us; speedup vs baseline: 1.1033x; 1.1033x over previous
//
#include <hip/hip_runtime.h>
#include <hip/hip_fp16.h>

#define N_NODES 50000
#define N_EDGES 800000
#define IN_FEATS 128
#define HD 128            // HEADS*OUT_FEATS
#define LOG2E 1.4426950408889634f

#define NB1 200           // pass-1 radix blocks
#define EPB1 4000         // edges per pass-1 block (200*4000 == E exactly)
#define NBUK 196          // buckets = ceil(N_NODES/256)
#define MTAB (NBUK * NB1) // 39200 histogram table entries (u16)
#define MB_SCAN 154       // ceil(MTAB/256)
#define EBUF 6144         // LDS edge staging per bucket (mean 4081, max ~4400)
#define PREPN 192         // prep blocks (192*256 == 24*4*64*8)
#define PGRID 782         // proj blocks = ceil((N_NODES/16)/4)

typedef __attribute__((ext_vector_type(8))) short bf16x8;
typedef __attribute__((ext_vector_type(4))) float floatx4;
typedef _Float16 h2 __attribute__((ext_vector_type(2)));

#if __has_builtin(__builtin_amdgcn_exp2f)
#define EXP2F(x) __builtin_amdgcn_exp2f(x)
#else
#define EXP2F(x) __expf((x) * 0.6931471805599453f)
#endif

static __device__ __forceinline__ unsigned short f2bf(float x) {
    unsigned int u = __float_as_uint(x);
    return (unsigned short)((u + 0x7FFFu + ((u >> 16) & 1u)) >> 16);   // RN-even
}
static __device__ __forceinline__ float bf2f(unsigned short h) {
    return __uint_as_float((unsigned int)h << 16);
}
static __device__ __forceinline__ unsigned int pk(float a, float b) {
    return (unsigned int)__half_as_ushort(__float2half(a)) |
           ((unsigned int)__half_as_ushort(__float2half(b)) << 16);
}
static __device__ __forceinline__ h2 u2h2(unsigned int u) {
    return __builtin_bit_cast(h2, u);
}

// ---------------------------------------------------------------------------
// K1: prep (weight swizzle into MFMA A-fragment order, log2e pre-scale) +
//     pass-1 radix histogram of dst>>8 (LDS atomics, u16 table).
// ---------------------------------------------------------------------------
__global__ __launch_bounds__(256) void prep_hist_kernel(
    const float* __restrict__ W0, const float* __restrict__ W1,
    const float* __restrict__ W2, unsigned short* __restrict__ Bsw,
    const int* __restrict__ dst, unsigned short* __restrict__ Htab) {
    __shared__ int h[NBUK];
    if (blockIdx.x < PREPN) {
        int idx = blockIdx.x * 256 + threadIdx.x;    // < 49152 exactly
        int j = idx & 7;
        int l = (idx >> 3) & 63;
        int q = (idx >> 9) & 3;
        int t = idx >> 11;                           // 0..23
        int k = q * 32 + ((l >> 4) << 3) + j;
        int c = ((t & 7) << 4) + (l & 15);
        int m = t >> 3;
        const float* W = (m == 0) ? W0 : ((m == 1) ? W1 : W2);
        float w = W[(size_t)c * IN_FEATS + k];
        if (m < 2) w *= LOG2E;
        Bsw[idx] = f2bf(w);
        return;
    }
    int blk = blockIdx.x - PREPN;                    // 0..NB1-1
    for (int i = threadIdx.x; i < NBUK; i += 256) h[i] = 0;
    __syncthreads();
    int base = blk * EPB1;
    for (int i = threadIdx.x; i < EPB1; i += 256)
        atomicAdd(&h[dst[base + i] >> 8], 1);
    __syncthreads();
    for (int b = threadIdx.x; b < NBUK; b += 256)
        Htab[b * NB1 + blk] = (unsigned short)h[b];  // counts <= 4000 < 65536
}

// ---------------------------------------------------------------------------
// K2: scan phase 1 — per-block sums (256 entries each) of u16 Htab.
// PARALLEL two-kernel scan (round 9's fused serial-prefix scan cost +18 us —
// variable-length dependent-load loop; do not re-fuse).
// ---------------------------------------------------------------------------
__global__ __launch_bounds__(256) void scan_partial(const unsigned short* __restrict__ cnt,
                                                    int* __restrict__ bsum, int n) {
    int i = blockIdx.x * 256 + threadIdx.x;
    int v = (i < n) ? (int)cnt[i] : 0;
#pragma unroll
    for (int d = 32; d > 0; d >>= 1) v += __shfl_down(v, d);
    __shared__ int ws[4];
    int lane = threadIdx.x & 63, w = threadIdx.x >> 6;
    if (lane == 0) ws[w] = v;
    __syncthreads();
    if (threadIdx.x == 0) bsum[blockIdx.x] = ws[0] + ws[1] + ws[2] + ws[3];
}

// ---------------------------------------------------------------------------
// K3: scan phase 2 — every block redundantly reduces bsum for its base, then
// writes its 256 exclusive offsets; last block writes grand total at out[n].
// ---------------------------------------------------------------------------
__global__ __launch_bounds__(256) void scan_write2(const unsigned short* __restrict__ cnt,
                                                   const int* __restrict__ bsum,
                                                   int* __restrict__ outp, int n, int nb) {
    int t = threadIdx.x, b = blockIdx.x;
    int va = (t < nb) ? bsum[t] : 0;
    int vb = (t < b) ? va : 0;
    int ra = va, rb = vb;
#pragma unroll
    for (int d = 32; d > 0; d >>= 1) { ra += __shfl_down(ra, d); rb += __shfl_down(rb, d); }
    __shared__ int sa[4], sb[4], ws2[4];
    int lane = t & 63, w = t >> 6;
    if (lane == 0) { sa[w] = ra; sb[w] = rb; }
    __syncthreads();
    int total = sa[0] + sa[1] + sa[2] + sa[3];
    int base  = sb[0] + sb[1] + sb[2] + sb[3];
    int i = b * 256 + t;
    int v = (i < n) ? (int)cnt[i] : 0;
    int x = v;
#pragma unroll
    for (int d = 1; d < 64; d <<= 1) { int up = __shfl_up(x, d); if (lane >= d) x += up; }
    if (lane == 63) ws2[w] = x;
    __syncthreads();
    for (int ww = 0; ww < w; ++ww) base += ws2[ww];
    if (i < n) outp[i] = base + x - v;
    if (b == (int)gridDim.x - 1 && t == 0) outp[n] = total;
}

// ---------------------------------------------------------------------------
// K4: fused MFMA projection + pass-1 scatter (precomputed HtabS bases).
// Proj: D = W . feat^T via mfma_16x16x32_bf16 (hi/lo bf16 split); each lane
// ends with 4 consecutive channels of one node -> dwordx4 to gsv (fs/fv fp16
// interleaved), dwordx2 to fdh. Scatter: counting-sort into tmp via LDS
// cursors. Zero global atomics.
// ---------------------------------------------------------------------------
__global__ __launch_bounds__(256) void proj_scatter_kernel(
    const float* __restrict__ feat, const unsigned short* __restrict__ Bsw,
    const float* __restrict__ b_src, const float* __restrict__ b_dst,
    const float* __restrict__ b_v,
    unsigned short* __restrict__ gsv, unsigned short* __restrict__ fdh,
    const int* __restrict__ src, const int* __restrict__ dst,
    const int* __restrict__ HtabS, unsigned int* __restrict__ tmp) {
    __shared__ int curl[NBUK];
    if (blockIdx.x >= PGRID) {
        int blk = blockIdx.x - PGRID;
        for (int b = threadIdx.x; b < NBUK; b += 256) curl[b] = HtabS[b * NB1 + blk];
        __syncthreads();
        int ebase = blk * EPB1;
        for (int i = threadIdx.x; i < EPB1; i += 256) {
            int d = dst[ebase + i];
            int s = src[ebase + i];
            int p = atomicAdd(&curl[d >> 8], 1);     // LDS atomic
            tmp[p] = (unsigned int)s | ((unsigned int)(d & 255) << 16);
        }
        return;
    }
    int wave = threadIdx.x >> 6, lane = threadIdx.x & 63;
    int tile = blockIdx.x * 4 + wave;
    if (tile >= N_NODES / 16) return;
    int row0 = tile * 16;
    int r16 = lane & 15, quad = lane >> 4;
    size_t node = (size_t)(row0 + r16);

    bf16x8 Fh[4], Fl[4];
    const float* frow = feat + node * IN_FEATS + quad * 8;
#pragma unroll
    for (int q = 0; q < 4; ++q) {
        float4 x0 = *(const float4*)(frow + q * 32);
        float4 x1 = *(const float4*)(frow + q * 32 + 4);
        float xs[8] = {x0.x, x0.y, x0.z, x0.w, x1.x, x1.y, x1.z, x1.w};
#pragma unroll
        for (int j = 0; j < 8; ++j) {
            unsigned short hh = f2bf(xs[j]);
            Fh[q][j] = (short)hh;
            Fl[q][j] = (short)f2bf(xs[j] - bf2f(hh));
        }
    }

#pragma unroll 1
    for (int tt = 0; tt < 8; ++tt) {
        floatx4 as = {0.f,0.f,0.f,0.f}, ad = {0.f,0.f,0.f,0.f}, av = {0.f,0.f,0.f,0.f};
#pragma unroll
        for (int q = 0; q < 4; ++q) {
            bf16x8 ws = *(const bf16x8*)(Bsw + ((((tt)      * 4 + q) * 64 + lane) << 3));
            bf16x8 wd = *(const bf16x8*)(Bsw + ((((8 + tt)  * 4 + q) * 64 + lane) << 3));
            bf16x8 wv = *(const bf16x8*)(Bsw + ((((16 + tt) * 4 + q) * 64 + lane) << 3));
            as = __builtin_amdgcn_mfma_f32_16x16x32_bf16(ws, Fh[q], as, 0, 0, 0);
            as = __builtin_amdgcn_mfma_f32_16x16x32_bf16(ws, Fl[q], as, 0, 0, 0);
            ad = __builtin_amdgcn_mfma_f32_16x16x32_bf16(wd, Fh[q], ad, 0, 0, 0);
            ad = __builtin_amdgcn_mfma_f32_16x16x32_bf16(wd, Fl[q], ad, 0, 0, 0);
            av = __builtin_amdgcn_mfma_f32_16x16x32_bf16(wv, Fh[q], av, 0, 0, 0);
            av = __builtin_amdgcn_mfma_f32_16x16x32_bf16(wv, Fl[q], av, 0, 0, 0);
        }
        int cbase = (tt << 4) + (quad << 2);
        float4 bs = *(const float4*)(b_src + cbase);
        float4 bd = *(const float4*)(b_dst + cbase);
        float4 bv = *(const float4*)(b_v   + cbase);
        uint4 o;
        o.x = pk(as[0] + bs.x * LOG2E, as[1] + bs.y * LOG2E);
        o.y = pk(av[0] + bv.x,         av[1] + bv.y);
        o.z = pk(as[2] + bs.z * LOG2E, as[3] + bs.w * LOG2E);
        o.w = pk(av[2] + bv.z,         av[3] + bv.w);
        *(uint4*)(gsv + node * 256 + (cbase << 1)) = o;
        uint2 od;
        od.x = pk(ad[0] + bd.x * LOG2E, ad[1] + bd.y * LOG2E);
        od.y = pk(ad[2] + bd.z * LOG2E, ad[3] + bd.w * LOG2E);
        *(uint2*)(fdh + node * 128 + cbase) = od;
    }
}

// ---------------------------------------------------------------------------
// K5: pass-2 bin. One block per bucket; LDS staging; coalesced ssort flush.
// ---------------------------------------------------------------------------
__global__ __launch_bounds__(256) void bin_kernel(
    const unsigned int* __restrict__ tmp, const int* __restrict__ HtabS,
    int* __restrict__ off, int* __restrict__ ssort) {
    __shared__ unsigned int ebuf[EBUF];
    __shared__ unsigned short obuf[EBUF];
    __shared__ int cnt_l[256];
    __shared__ int wsum[4];
    int b = blockIdx.x, t = threadIdx.x, lane = t & 63, w = t >> 6;
    int start = HtabS[b * NB1];
    int end = (b == NBUK - 1) ? N_EDGES : HtabS[(b + 1) * NB1];
    int cnt0 = end - start;
    cnt_l[t] = 0;
    __syncthreads();
    bool staged = (cnt0 <= EBUF);
    for (int i = t; i < cnt0; i += 256) {
        unsigned int e = tmp[start + i];
        if (staged) ebuf[i] = e;
        atomicAdd(&cnt_l[e >> 16], 1);
    }
    __syncthreads();
    int v = cnt_l[t];
    int x = v;
#pragma unroll
    for (int d = 1; d < 64; d <<= 1) { int up = __shfl_up(x, d); if (lane >= d) x += up; }
    if (lane == 63) wsum[w] = x;
    __syncthreads();
    int basex = 0;
    for (int ww = 0; ww < w; ++ww) basex += wsum[ww];
    int excl = basex + x - v;                  // exclusive within bucket
    int node = b * 256 + t;
    if (node < N_NODES) off[node] = start + excl;
    if (b == NBUK - 1) {
        if (t == 0) off[N_NODES] = N_EDGES;
        if (t < 8) ssort[N_EDGES + t] = 0;     // pads for gather prefetch
    }
    __syncthreads();
    cnt_l[t] = excl;                           // becomes cursor
    __syncthreads();
    if (staged) {
        for (int i = t; i < cnt0; i += 256) {
            unsigned int e = ebuf[i];
            int p = atomicAdd(&cnt_l[e >> 16], 1);
            obuf[p] = (unsigned short)(e & 0xFFFFu);
        }
        __syncthreads();
        for (int i = t; i < cnt0; i += 256)    // coalesced flush
            ssort[start + i] = (int)obuf[i];
    } else {
        for (int i = t; i < cnt0; i += 256) {
            unsigned int e = tmp[start + i];
            int p = atomicAdd(&cnt_l[e >> 16], 1);
            ssort[start + p] = (int)(e & 0xFFFFu);
        }
    }
}

// ---------------------------------------------------------------------------
// K6: gather. One wave per dst node, channel pair per lane (uint2 per edge
// row, one full row per wave-load). Four interleaved software-pipelined edge
// streams for MLP. Wave-uniform control (scalar selects); packed fp16 logit
// math (leaky via 0.6a+0.4|a|), exp2 (weights pre-scaled), fp32 accumulation.
// ---------------------------------------------------------------------------
__global__ __launch_bounds__(128) void gather_kernel(
    const unsigned short* __restrict__ gsv, const unsigned short* __restrict__ fdh,
    const int* __restrict__ off, const int* __restrict__ ssort,
    float* __restrict__ out, int n) {
    int wid = __builtin_amdgcn_readfirstlane((int)((blockIdx.x * 128 + threadIdx.x) >> 6));
    int lane = threadIdx.x & 63;
    if (wid >= n) return;
    unsigned int fdu = *(const unsigned int*)(fdh + (size_t)wid * 128 + lane * 2);
    h2 fd2 = u2h2(fdu);
    const h2 c06 = {(_Float16)0.6f, (_Float16)0.6f};
    const h2 c04 = {(_Float16)0.4f, (_Float16)0.4f};

    float nx[4], ny[4], dx[4], dy[4];
#pragma unroll
    for (int k = 0; k < 4; ++k) { nx[k] = 0.f; ny[k] = 0.f; dx[k] = 0.f; dy[k] = 0.f; }

    int beg = off[wid], end = off[wid + 1];
    int deg = end - beg;
    int iters = (deg + 3) >> 2;

    if (iters > 0) {
        uint2 g[4];
#pragma unroll
        for (int k = 0; k < 4; ++k) {
            int idx = beg + k;
            int s = (idx < end) ? ssort[idx] : 0;
            g[k] = *(const uint2*)(gsv + (size_t)s * 256 + lane * 4);
        }
        for (int j = 0; j < iters; ++j) {
            int b4 = beg + 4 * j + 4;
            uint2 gn[4];
#pragma unroll
            for (int k = 0; k < 4; ++k) {
                int idx = b4 + k;                       // <= end+6 <= E+6 (8 pads)
                int s = (idx < end) ? ssort[idx] : 0;   // row 0 stays cache-hot
                gn[k] = *(const uint2*)(gsv + (size_t)s * 256 + lane * 4);
            }
#pragma unroll
            for (int k = 0; k < 4; ++k) {
                h2 fs = u2h2(g[k].x);
                h2 a = fs + fd2;                                        // v_pk_add_f16
                h2 aa = u2h2(__builtin_bit_cast(unsigned int, a) & 0x7FFF7FFFu);
                h2 al = a * c06 + aa * c04;                             // pk_mul + pk_fma
                float x0 = EXP2F((float)al.x);
                float x1 = EXP2F((float)al.y);
                bool valid = (4 * j + k) < deg;                         // wave-uniform
                if (!valid) { x0 = 0.f; x1 = 0.f; }
                float2 fv = __half22float2(*(const __half2*)&g[k].y);
                dx[k] += x0; dy[k] += x1;
                nx[k] = fmaf(x0, fv.x, nx[k]); ny[k] = fmaf(x1, fv.y, ny[k]);
                g[k] = gn[k];
            }
        }
    }
    float dxs = (dx[0] + dx[1]) + (dx[2] + dx[3]);
    float dys = (dy[0] + dy[1]) + (dy[2] + dy[3]);
    float nxs = (nx[0] + nx[1]) + (nx[2] + nx[3]);
    float nys = (ny[0] + ny[1]) + (ny[2] + ny[3]);
    float2 o;
    o.x = (dxs > 0.f) ? nxs / dxs : 0.f;
    o.y = (dys > 0.f) ? nys / dys : 0.f;
    *(float2*)&out[(size_t)wid * HD + lane * 2] = o;
}

// ---------------------------------------------------------------------------
extern "C" void kernel_launch(void* const* d_in, const int* in_sizes, int n_in,
                              void* d_out, int out_size, void* d_ws, size_t ws_size,
                              hipStream_t stream) {
    const float* feat  = (const float*)d_in[0];
    const float* W_src = (const float*)d_in[1];
    const float* b_src = (const float*)d_in[2];
    const float* W_dst = (const float*)d_in[3];
    const float* b_dst = (const float*)d_in[4];
    const float* W_v   = (const float*)d_in[5];
    const float* b_v   = (const float*)d_in[6];
    const int*   src   = (const int*)d_in[7];
    const int*   dst   = (const int*)d_in[8];
    float* out = (float*)d_out;

    // workspace layout
    unsigned short* gsv  = (unsigned short*)d_ws;                // N*256 u16
    unsigned short* fdh  = gsv + (size_t)N_NODES * 256;          // N*128 u16
    unsigned short* Bsw  = fdh + (size_t)N_NODES * 128;          // 49152 u16
    unsigned short* Htab = Bsw + 24 * 4 * 64 * 8;                // MTAB u16
    int* HtabS = (int*)(Htab + MTAB);                            // MTAB+1 int
    int* bsum  = HtabS + MTAB + 1;                               // 256
    int* off   = bsum + 256;                                     // N+1
    int* ssort = off + (N_NODES + 1);                            // E+8
    unsigned int* tmp = (unsigned int*)(ssort + N_EDGES + 8);    // E

    prep_hist_kernel<<<PREPN + NB1, 256, 0, stream>>>(W_src, W_dst, W_v, Bsw, dst, Htab);

    scan_partial<<<MB_SCAN, 256, 0, stream>>>(Htab, bsum, MTAB);
    scan_write2<<<MB_SCAN, 256, 0, stream>>>(Htab, bsum, HtabS, MTAB, MB_SCAN);

    proj_scatter_kernel<<<PGRID + NB1, 256, 0, stream>>>(
        feat, Bsw, b_src, b_dst, b_v, gsv, fdh, src, dst, HtabS, tmp);

    bin_kernel<<<NBUK, 256, 0, stream>>>(tmp, HtabS, off, ssort);

    gather_kernel<<<(N_NODES * 64) / 128, 128, 0, stream>>>(gsv, fdh, off, ssort, out, N_NODES);
}